// Round 19
// baseline (122.867 us; speedup 1.0000x reference)
//
#include <hip/hip_runtime.h>
#include <hip/hip_bf16.h>

// Problem constants
#define BB 2
#define SS 2048
#define DD 64
#define HH 8
#define HD 512            // HH*DD
#define SCALE 0.125f      // 1/sqrt(64)

typedef __bf16 bf16;
typedef __attribute__((ext_vector_type(4))) __bf16 bf16x4;
typedef __attribute__((ext_vector_type(8))) __bf16 bf16x8;
typedef __attribute__((ext_vector_type(4))) float floatx4;

#define PSLOT 2097152     // bf16 elements per partial slot = BB*HH*SS*DD (4 MiB)

__device__ __forceinline__ floatx4 mfma16(bf16x8 a, bf16x8 b, floatx4 c) {
    return __builtin_amdgcn_mfma_f32_16x16x32_bf16(a, b, c, 0, 0, 0);
}

// v_mfma_f32_16x16x16_bf16 via inline asm (ISA-documented on gfx950).
// Hazard recognizer can't see inside asm: embedded s_nop 1 guarantees the
// >=2 wait states between VALU writes of A/B and the MFMA read.
#define PV_MFMA(ACC, A, B) \
    asm("s_nop 1\n\tv_mfma_f32_16x16x16_bf16 %0, %1, %2, %0" \
        : "+v"(ACC) : "v"(A), "v"(B))

// drain MFMA pipe before VALU reads of asm-MFMA results (16 cycles)
#define MFMA_DRAIN4(A0, A1, A2, A3) \
    asm volatile("s_nop 7\n\ts_nop 7" : "+v"(A0), "+v"(A1), "+v"(A2), "+v"(A3))

// async global->LDS, 16 B/lane. LDS dest = wave-uniform base + lane*16 (HW).
#define GLL(G, L) __builtin_amdgcn_global_load_lds( \
    (const __attribute__((address_space(1))) void*)(G), \
    (__attribute__((address_space(3))) void*)(L), 16, 0, 0)

__device__ __forceinline__ bf16x8 load8(const void* base, size_t idx, int f32) {
    if (f32) {
        const float* p = (const float*)base + idx;
        const float4 a = *reinterpret_cast<const float4*>(p);
        const float4 b = *reinterpret_cast<const float4*>(p + 4);
        bf16x8 r;
        r[0] = (bf16)a.x; r[1] = (bf16)a.y; r[2] = (bf16)a.z; r[3] = (bf16)a.w;
        r[4] = (bf16)b.x; r[5] = (bf16)b.y; r[6] = (bf16)b.z; r[7] = (bf16)b.w;
        return r;
    }
    return *reinterpret_cast<const bf16x8*>((const bf16*)base + idx);
}

__device__ __forceinline__ float load1(const void* base, int idx, int f32) {
    return f32 ? ((const float*)base)[idx] : (float)((const bf16*)base)[idx];
}

// ---------------------------------------------------------------------------
// Kernel 1 (R17-validated, unchanged): QKV proj + RoPE + norms, 4 s-tiles
// per wave; W frags + RoPE freq constants amortized 4x.
// ---------------------------------------------------------------------------
__global__ __launch_bounds__(256) void proj_rope_kernel(
    const void* __restrict__ q, const void* __restrict__ Wq,
    const void* __restrict__ Wk, const void* __restrict__ Wv,
    bf16* __restrict__ qh, bf16* __restrict__ kh, bf16* __restrict__ vt,
    float* __restrict__ qn, float* __restrict__ kn,
    int* __restrict__ flagw)
{
    const int lane = threadIdx.x & 63;
    const int wid  = blockIdx.x * 4 + (threadIdx.x >> 6);
    if (wid >= 3 * BB * HH * (SS / 64)) return;       // 1536 work items
    const int l16  = lane & 15;
    const int quad = lane >> 4;

    // inline dtype detection over q's first 1024 halfwords (per-wave ballot)
    int hit = 0;
    const unsigned short* qu = (const unsigned short*)q;
#pragma unroll
    for (int i = 0; i < 16; ++i) {
        const unsigned short u = qu[lane + i * 64];
        if (((u >> 7) & 0xFF) >= 134) hit = 1;
    }
    const int f32 = (__ballot(hit) != 0ull) ? 1 : 0;
    if (wid == 0 && lane == 0) *flagw = f32;

    int id = wid;                        // ((w*BB + b)*(SS/64) + st4)*HH + h
    const int h   = id % HH; id /= HH;
    const int st4 = id % (SS / 64); id /= (SS / 64);
    const int b   = id % BB; id /= BB;
    const int w   = id;                  // 0=q, 1=k, 2=v

    const void* W = (w == 0) ? Wq : (w == 1) ? Wk : Wv;
    const size_t bh = (size_t)b * HH + h;

    // W frags once (A-operand for Q/K swapped form; B-operand for V)
    bf16x8 wb0[4], wb1[4];
#pragma unroll
    for (int t = 0; t < 4; ++t) {
        const size_t wrow = (size_t)(h * 64 + t * 16 + l16) * DD;
        wb0[t] = load8(W, wrow + quad * 8, f32);
        wb1[t] = load8(W, wrow + quad * 8 + 32, f32);
    }

    // RoPE frequency constants once per t (depend only on d)
    float frevA[4], frevB[4];
    if (w < 2) {
#pragma unroll
        for (int t = 0; t < 4; ++t) {
            const int dbase = t * 16 + quad * 4;      // even
            frevA[t] = __builtin_amdgcn_exp2f(
                -(float)dbase * (13.2877123795f / 64.0f)) * 0.15915494309f;
            frevB[t] = __builtin_amdgcn_exp2f(
                -(float)(dbase + 2) * (13.2877123795f / 64.0f)) * 0.15915494309f;
        }
    }

    for (int s4 = 0; s4 < 4; ++s4) {
        const int s0 = (st4 * 4 + s4) * 16;
        const size_t qrow = ((size_t)b * SS + s0 + l16) * DD;
        bf16x8 a0 = load8(q, qrow + quad * 8, f32);
        bf16x8 a1 = load8(q, qrow + quad * 8 + 32, f32);

        floatx4 cv[4];
#pragma unroll
        for (int t = 0; t < 4; ++t) {
            floatx4 acc = {0.f, 0.f, 0.f, 0.f};
            if (w < 2) {        // swapped: C[m=d_local][n=s_local]
                acc = mfma16(wb0[t], a0, acc);
                acc = mfma16(wb1[t], a1, acc);
            } else {            // unswapped: C[m=s_local][n=d_local]
                acc = mfma16(a0, wb0[t], acc);
                acc = mfma16(a1, wb1[t], acc);
            }
            cv[t] = acc;
        }

        if (w < 2) {
            bf16*  dst  = (w == 0) ? qh : kh;
            float* ndst = (w == 0) ? qn : kn;
            const float srowf = (float)(s0 + l16);
            float nacc = 0.f;
            bf16* drow = dst + (bh * SS + s0 + l16) * DD + quad * 4;
#pragma unroll
            for (int t = 0; t < 4; ++t) {
                float revA = srowf * frevA[t]; revA -= floorf(revA);
                float revB = srowf * frevB[t]; revB -= floorf(revB);
                const float snA = __builtin_amdgcn_sinf(revA);
                const float csA = __builtin_amdgcn_cosf(revA);
                const float snB = __builtin_amdgcn_sinf(revB);
                const float csB = __builtin_amdgcn_cosf(revB);
                const float x0 = cv[t][0], x1 = cv[t][1];
                const float x2 = cv[t][2], x3 = cv[t][3];
                const float r0 = x0 * csA - x1 * snA;
                const float r1 = x0 * snA + x1 * csA;
                const float r2 = x2 * csB - x3 * snB;
                const float r3 = x2 * snB + x3 * csB;
                nacc += r0 * r0 + r1 * r1 + r2 * r2 + r3 * r3;
                bf16x4 o; o[0]=(bf16)r0; o[1]=(bf16)r1; o[2]=(bf16)r2; o[3]=(bf16)r3;
                *reinterpret_cast<bf16x4*>(drow + t * 16) = o;
            }
            nacc += __shfl_xor(nacc, 16);
            nacc += __shfl_xor(nacc, 32);
            if (quad == 0) ndst[bh * SS + s0 + l16] = nacc;
        } else {
            // tile-major V: [bh][st][dhi=t][dlo=l16][klocal=quad*4+r]
            bf16* vrow = vt + ((size_t)bh * 128 + st4 * 4 + s4) * 1024
                       + l16 * 16 + quad * 4;
#pragma unroll
            for (int t = 0; t < 4; ++t) {
                bf16x4 pv;
#pragma unroll
                for (int r = 0; r < 4; ++r) pv[r] = (bf16)cv[t][r];
                *reinterpret_cast<bf16x4*>(vrow + t * 256) = pv;
            }
        }
    }
}

// ---------------------------------------------------------------------------
// Kernel 2: LDS-staged attn, 64-KEY CHUNKS (R16/R18 math, barrier count
// halved). Block = 4 waves on 4 consecutive qt of one (bh, slot); each
// 64-key chunk staged once per block (K 8KB swizzled + V 8KB, 4 GLL/thread),
// double-buffered (32 KB LDS), ONE barrier per 64 keys. Key-ascending
// accumulation order preserved -> bit-identical results vs R18.
// Slot spans are 64-multiples at ksh=9/10/11 -> nch block-uniform.
// ---------------------------------------------------------------------------
__global__ __launch_bounds__(256) void attn_kernel(
    const bf16* __restrict__ qh, const bf16* __restrict__ kh,
    const bf16* __restrict__ vt, const float* __restrict__ qn,
    const float* __restrict__ kn, const void* __restrict__ gamma,
    bf16* __restrict__ partial, const int* __restrict__ flagp,
    int ksh, int pb)
{
    __shared__ __align__(16) char smem[32768];  // K: 2x8KB @0; V: 2x8KB @16384
    const int f32  = *flagp;
    const int tid  = threadIdx.x;
    const int wv   = tid >> 6;
    const int lane = tid & 63;
    const int l16  = lane & 15;
    const int quad = lane >> 4;

    // XCD-pinned: bh%8 == blockIdx%8; grid = 16 * pb blocks
    const int xcd  = blockIdx.x & 7;
    int sblk = blockIdx.x >> 3;
    const int half = (sblk >= pb) ? 1 : 0;
    const int bh   = xcd + (half << 3);
    sblk -= half * pb;
    // decode (q4, slot): quad-group q4 has ((q4*64+63)>>ksh)+1 active slots
    int q4 = 0;
    for (;;) {
        const int ns = ((q4 * 64 + 63) >> ksh) + 1;
        if (sblk < ns) break;
        sblk -= ns; ++q4;
    }
    const int slot = sblk;
    const int qt   = q4 * 4 + wv;
    const int s0   = qt * 16;
    const int tb   = slot << ksh;
    const int te   = min(tb + (1 << ksh), (q4 + 1) * 64);
    const int nch  = (te - tb) >> 6;    // 64-key chunks, block-uniform
    const int h    = bh & 7;

    const float cc = load1(gamma, h, f32) * SCALE * 1.4426950408889634f;

    const bf16* qbase = qh + ((size_t)bh * SS + s0 + l16) * DD;
    bf16x8 aq0 = *reinterpret_cast<const bf16x8*>(qbase + quad * 8);
    bf16x8 aq1 = *reinterpret_cast<const bf16x8*>(qbase + quad * 8 + 32);
    const float qn_l = qn[(size_t)bh * SS + s0 + l16];

    floatx4 acc0 = {0.f,0.f,0.f,0.f}, acc1 = {0.f,0.f,0.f,0.f};
    floatx4 acc2 = {0.f,0.f,0.f,0.f}, acc3 = {0.f,0.f,0.f,0.f};

    const float* knp   = kn + (size_t)bh * SS + quad * 4;       // + key
    const char* kgbase = (const char*)(kh + (size_t)bh * SS * DD);  // + t0*128
    const char* vgbase = (const char*)(vt + (size_t)bh * 131072);   // + kt*2048

    // staging maps: this thread stages cells jA = wv*64+lane and jA+256
    const int jA = wv * 64 + lane, jB = jA + 256;
    const int keyA = jA >> 3, keyB = jB >> 3;
    const int goffKA = keyA * 128 + ((((jA & 7) - keyA) & 7)) * 16;
    const int goffKB = keyB * 128 + ((((jB & 7) - keyB) & 7)) * 16;
    const int goffVA = jA * 16;
    const int goffVB = jB * 16;
    char* ldsKA = smem + wv * 1024;                 // + buf*8192
    char* ldsKB = smem + 4096 + wv * 1024;
    char* ldsVA = smem + 16384 + wv * 1024;
    char* ldsVB = smem + 16384 + 4096 + wv * 1024;

    // swizzled K frag offsets within an 8KB K buffer (16-key tiles at
    // +0/+2048/+4096/+6144; swizzle invariant across tiles since 16%8==0)
    const int kro0 = (l16 * 8 + ((quad + l16) & 7)) * 16;
    const int kro1 = (l16 * 8 + ((quad + 4 + l16) & 7)) * 16;
    const int vro  = l16 * 32 + quad * 8;      // + nb*512 within a V tile

    // prologue: stage chunk 0 (64 keys) into buf 0
    GLL(kgbase + (size_t)tb * 128 + goffKA, ldsKA);
    GLL(kgbase + (size_t)tb * 128 + goffKB, ldsKB);
    GLL(vgbase + (size_t)(tb >> 4) * 2048 + goffVA, ldsVA);
    GLL(vgbase + (size_t)(tb >> 4) * 2048 + goffVB, ldsVB);
    __syncthreads();

    int buf = 0, t0 = tb;
    for (int c = 0; c < nch; ++c, t0 += 64) {
        if (c + 1 < nch) {   // async prefetch next 64-key chunk
            const size_t kg = (size_t)(t0 + 64) * 128;
            const size_t vg = (size_t)((t0 + 64) >> 4) * 2048;
            const int ob = (buf ^ 1) << 13;
            GLL(kgbase + kg + goffKA, ldsKA + ob);
            GLL(kgbase + kg + goffKB, ldsKB + ob);
            GLL(vgbase + vg + goffVA, ldsVA + ob);
            GLL(vgbase + vg + goffVB, ldsVB + ob);
        }
        const char* Kb = smem + (buf << 13);
        const char* Vb = smem + 16384 + (buf << 13);

#pragma unroll
        for (int hh = 0; hh < 2; ++hh) {     // two 32-key halves, ascending
            const int th = t0 + hh * 32;
            const char* Kh = Kb + hh * 4096;
            const char* Vh = Vb + hh * 4096;
            const float4 knv0 = *reinterpret_cast<const float4*>(knp + th);
            const float4 knv1 = *reinterpret_cast<const float4*>(knp + th + 16);

            bf16x8 kc0 = *reinterpret_cast<const bf16x8*>(Kh + kro0);
            bf16x8 kc1 = *reinterpret_cast<const bf16x8*>(Kh + kro1);
            bf16x8 kc2 = *reinterpret_cast<const bf16x8*>(Kh + 2048 + kro0);
            bf16x8 kc3 = *reinterpret_cast<const bf16x8*>(Kh + 2048 + kro1);
            bf16x4 v00 = *reinterpret_cast<const bf16x4*>(Vh + vro);
            bf16x4 v01 = *reinterpret_cast<const bf16x4*>(Vh + 512 + vro);
            bf16x4 v02 = *reinterpret_cast<const bf16x4*>(Vh + 1024 + vro);
            bf16x4 v03 = *reinterpret_cast<const bf16x4*>(Vh + 1536 + vro);
            bf16x4 v10 = *reinterpret_cast<const bf16x4*>(Vh + 2048 + vro);
            bf16x4 v11 = *reinterpret_cast<const bf16x4*>(Vh + 2560 + vro);
            bf16x4 v12 = *reinterpret_cast<const bf16x4*>(Vh + 3072 + vro);
            bf16x4 v13 = *reinterpret_cast<const bf16x4*>(Vh + 3584 + vro);

            floatx4 z0 = {0.f,0.f,0.f,0.f};
            z0 = mfma16(kc0, aq0, z0);
            z0 = mfma16(kc1, aq1, z0);
            floatx4 z1 = {0.f,0.f,0.f,0.f};
            z1 = mfma16(kc2, aq0, z1);
            z1 = mfma16(kc3, aq1, z1);

            const float* k0_ = (const float*)&knv0;
            const float* k1_ = (const float*)&knv1;
            bf16x4 p0, p1;
            if (th + 31 <= s0) {             // fully causal for this wave
#pragma unroll
                for (int i = 0; i < 4; ++i) {
                    float rawA = fmaf(-2.f, z0[i], qn_l + k0_[i]);
                    float rawB = fmaf(-2.f, z1[i], qn_l + k1_[i]);
                    p0[i] = (bf16)__builtin_amdgcn_exp2f(fminf(-cc * rawA, 0.f));
                    p1[i] = (bf16)__builtin_amdgcn_exp2f(fminf(-cc * rawB, 0.f));
                }
            } else {                         // diagonal/acausal: key<=query
                const int dq0 = s0 + l16 - th - quad * 4;
                const int dq1 = dq0 - 16;
#pragma unroll
                for (int i = 0; i < 4; ++i) {
                    float rawA = fmaf(-2.f, z0[i], qn_l + k0_[i]);
                    float rawB = fmaf(-2.f, z1[i], qn_l + k1_[i]);
                    float eA = __builtin_amdgcn_exp2f(fminf(-cc * rawA, 0.f));
                    float eB = __builtin_amdgcn_exp2f(fminf(-cc * rawB, 0.f));
                    p0[i] = (bf16)((i <= dq0) ? eA : 0.f);
                    p1[i] = (bf16)((i <= dq1) ? eB : 0.f);
                }
            }

            PV_MFMA(acc0, v00, p0);
            PV_MFMA(acc1, v01, p0);
            PV_MFMA(acc2, v02, p0);
            PV_MFMA(acc3, v03, p0);
            PV_MFMA(acc0, v10, p1);
            PV_MFMA(acc1, v11, p1);
            PV_MFMA(acc2, v12, p1);
            PV_MFMA(acc3, v13, p1);
        }

        __syncthreads();    // staging done + all reads of buf done
        buf ^= 1;
    }

    MFMA_DRAIN4(acc0, acc1, acc2, acc3);

    // O^T C-frag: col=query=l16, row=d_local=quad*4+r -> bf16x4 per nb.
    bf16* pbp = partial + (size_t)slot * PSLOT
              + ((size_t)bh * SS + s0 + l16) * DD + quad * 4;
    bf16x4 o;
#define STORE4(PTR, ACC) \
    o[0]=(bf16)(ACC)[0]; o[1]=(bf16)(ACC)[1]; o[2]=(bf16)(ACC)[2]; o[3]=(bf16)(ACC)[3]; \
    *reinterpret_cast<bf16x4*>(PTR) = o;
    STORE4(pbp +  0, acc0)
    STORE4(pbp + 16, acc1)
    STORE4(pbp + 32, acc2)
    STORE4(pbp + 48, acc3)
#undef STORE4
}

// ---------------------------------------------------------------------------
// Kernel 3 (R8/R12-validated, unchanged): fused split-K reduce + output proj.
// ---------------------------------------------------------------------------
template <int NACT>
__device__ __forceinline__ floatx4 opj_core(const bf16* __restrict__ partial,
                                            const void* __restrict__ Wo,
                                            int b, int srow, size_t brow,
                                            int f32, int quad) {
    floatx4 acc = {0.f, 0.f, 0.f, 0.f};
#pragma unroll 4
    for (int kk = 0; kk < HD; kk += 32) {
        const int h  = kk >> 6;
        const int d0 = (kk & 63) + quad * 8;
        const bf16* ap = partial + (((size_t)(b * 8 + h)) * SS + srow) * 64 + d0;
        bf16x8 v0 = *reinterpret_cast<const bf16x8*>(ap);
        float u[8];
#pragma unroll
        for (int i = 0; i < 8; ++i) u[i] = (float)v0[i];
#pragma unroll
        for (int s = 1; s < NACT; ++s) {
            bf16x8 vs = *reinterpret_cast<const bf16x8*>(ap + (size_t)s * PSLOT);
#pragma unroll
            for (int i = 0; i < 8; ++i) u[i] += (float)vs[i];
        }
        bf16x8 a;
#pragma unroll
        for (int i = 0; i < 8; ++i) a[i] = (bf16)u[i];
        bf16x8 w = load8(Wo, brow + kk, f32);
        acc = mfma16(a, w, acc);
    }
    return acc;
}

__global__ __launch_bounds__(256) void outproj_kernel(
    const bf16* __restrict__ partial, const void* __restrict__ Wo,
    void* __restrict__ out, const int* __restrict__ flagp, int ksh)
{
    const int f32  = *flagp;
    const int ct   = threadIdx.x >> 6;
    const int lane = threadIdx.x & 63;
    const int l16  = lane & 15;
    const int quad = lane >> 4;

    const int g0   = blockIdx.x * 16;          // global row (b*SS + s)
    const int b    = g0 >> 11;
    const int s0   = g0 & (SS - 1);
    const int nact = (s0 >> ksh) + 1;
    const int srow = s0 + l16;
    const size_t brow = (size_t)(ct * 16 + l16) * HD + quad * 8;

    floatx4 acc;
    switch (nact) {
        case 1:  acc = opj_core<1>(partial, Wo, b, srow, brow, f32, quad); break;
        case 2:  acc = opj_core<2>(partial, Wo, b, srow, brow, f32, quad); break;
        case 3:  acc = opj_core<3>(partial, Wo, b, srow, brow, f32, quad); break;
        default: acc = opj_core<4>(partial, Wo, b, srow, brow, f32, quad); break;
    }

#pragma unroll
    for (int r = 0; r < 4; ++r) {
        const size_t o = (size_t)(g0 + quad * 4 + r) * DD + ct * 16 + l16;
        if (f32) ((float*)out)[o] = acc[r];
        else     ((bf16*)out)[o]  = (bf16)acc[r];
    }
}

// ---------------------------------------------------------------------------
extern "C" void kernel_launch(void* const* d_in, const int* in_sizes, int n_in,
                              void* d_out, int out_size, void* d_ws, size_t ws_size,
                              hipStream_t stream) {
    const void* q     = d_in[0];
    const void* Wq    = d_in[1];
    const void* Wk    = d_in[2];
    const void* Wv    = d_in[3];
    const void* Wo    = d_in[4];
    const void* gamma = d_in[5];

    char* ws = (char*)d_ws;
    bf16*  qh      = (bf16*)(ws);                    // 4 MiB
    bf16*  kh      = (bf16*)(ws + 4194304);          // 4 MiB
    bf16*  vt      = (bf16*)(ws + 8388608);          // 4 MiB (tile-major)
    float* qn      = (float*)(ws + 12582912);        // 128 KiB
    float* kn      = (float*)(ws + 12713984);        // 128 KiB
    int*   flag    = (int*)  (ws + 12845056);
    bf16*  partial = (bf16*)(ws + 13631488);         // nslot x 4 MiB (bf16)

    // split-K tier: 4 slots preferred (ksh=9); spans stay 64-multiples.
    int ksh = 11;
    const size_t base = 13631488ull;
    if      (ws_size >= base + 4ull * 4194304) ksh = 9;
    else if (ws_size >= base + 2ull * 4194304) ksh = 10;

    // blocks per bh: one block per (qt-quad q4, active slot)
    int pb = 0;
    for (int q4 = 0; q4 < 32; ++q4) pb += ((q4 * 64 + 63) >> ksh) + 1;

    const int nproj = 3 * BB * HH * (SS / 64);       // 1536 proj work items
    proj_rope_kernel<<<dim3((nproj + 3) / 4), dim3(256), 0, stream>>>(
        q, Wq, Wk, Wv, qh, kh, vt, qn, kn, flag);
    // XCD-pinned grid: 8 xcds x 2 bh-halves x pb blocks
    attn_kernel<<<dim3(16 * pb), dim3(256), 0, stream>>>(
        qh, kh, vt, qn, kn, gamma, partial, flag, ksh, pb);
    outproj_kernel<<<dim3(BB * SS / 16), dim3(256), 0, stream>>>(
        partial, Wo, d_out, flag, ksh);
}

// Round 20
// 120.691 us; speedup vs baseline: 1.0180x; 1.0180x over previous
//
#include <hip/hip_runtime.h>
#include <hip/hip_bf16.h>

// Problem constants
#define BB 2
#define SS 2048
#define DD 64
#define HH 8
#define HD 512            // HH*DD
#define SCALE 0.125f      // 1/sqrt(64)

typedef __bf16 bf16;
typedef __attribute__((ext_vector_type(4))) __bf16 bf16x4;
typedef __attribute__((ext_vector_type(8))) __bf16 bf16x8;
typedef __attribute__((ext_vector_type(4))) float floatx4;

#define PSLOT 2097152     // bf16 elements per partial slot = BB*HH*SS*DD (4 MiB)

__device__ __forceinline__ floatx4 mfma16(bf16x8 a, bf16x8 b, floatx4 c) {
    return __builtin_amdgcn_mfma_f32_16x16x32_bf16(a, b, c, 0, 0, 0);
}

// v_mfma_f32_16x16x16_bf16 via inline asm (ISA-documented on gfx950).
// Hazard recognizer can't see inside asm: embedded s_nop 1 guarantees the
// >=2 wait states between VALU writes of A/B and the MFMA read.
#define PV_MFMA(ACC, A, B) \
    asm("s_nop 1\n\tv_mfma_f32_16x16x16_bf16 %0, %1, %2, %0" \
        : "+v"(ACC) : "v"(A), "v"(B))

// drain MFMA pipe before VALU reads of asm-MFMA results (16 cycles)
#define MFMA_DRAIN4(A0, A1, A2, A3) \
    asm volatile("s_nop 7\n\ts_nop 7" : "+v"(A0), "+v"(A1), "+v"(A2), "+v"(A3))

// async global->LDS, 16 B/lane. LDS dest = wave-uniform base + lane*16 (HW).
#define GLL(G, L) __builtin_amdgcn_global_load_lds( \
    (const __attribute__((address_space(1))) void*)(G), \
    (__attribute__((address_space(3))) void*)(L), 16, 0, 0)

__device__ __forceinline__ bf16x8 load8(const void* base, size_t idx, int f32) {
    if (f32) {
        const float* p = (const float*)base + idx;
        const float4 a = *reinterpret_cast<const float4*>(p);
        const float4 b = *reinterpret_cast<const float4*>(p + 4);
        bf16x8 r;
        r[0] = (bf16)a.x; r[1] = (bf16)a.y; r[2] = (bf16)a.z; r[3] = (bf16)a.w;
        r[4] = (bf16)b.x; r[5] = (bf16)b.y; r[6] = (bf16)b.z; r[7] = (bf16)b.w;
        return r;
    }
    return *reinterpret_cast<const bf16x8*>((const bf16*)base + idx);
}

__device__ __forceinline__ float load1(const void* base, int idx, int f32) {
    return f32 ? ((const float*)base)[idx] : (float)((const bf16*)base)[idx];
}

// ---------------------------------------------------------------------------
// Kernel 1 (R17-validated, unchanged): QKV proj + RoPE + norms, 4 s-tiles
// per wave; W frags + RoPE freq constants amortized 4x.
// ---------------------------------------------------------------------------
__global__ __launch_bounds__(256) void proj_rope_kernel(
    const void* __restrict__ q, const void* __restrict__ Wq,
    const void* __restrict__ Wk, const void* __restrict__ Wv,
    bf16* __restrict__ qh, bf16* __restrict__ kh, bf16* __restrict__ vt,
    float* __restrict__ qn, float* __restrict__ kn,
    int* __restrict__ flagw)
{
    const int lane = threadIdx.x & 63;
    const int wid  = blockIdx.x * 4 + (threadIdx.x >> 6);
    if (wid >= 3 * BB * HH * (SS / 64)) return;       // 1536 work items
    const int l16  = lane & 15;
    const int quad = lane >> 4;

    // inline dtype detection over q's first 1024 halfwords (per-wave ballot)
    int hit = 0;
    const unsigned short* qu = (const unsigned short*)q;
#pragma unroll
    for (int i = 0; i < 16; ++i) {
        const unsigned short u = qu[lane + i * 64];
        if (((u >> 7) & 0xFF) >= 134) hit = 1;
    }
    const int f32 = (__ballot(hit) != 0ull) ? 1 : 0;
    if (wid == 0 && lane == 0) *flagw = f32;

    int id = wid;                        // ((w*BB + b)*(SS/64) + st4)*HH + h
    const int h   = id % HH; id /= HH;
    const int st4 = id % (SS / 64); id /= (SS / 64);
    const int b   = id % BB; id /= BB;
    const int w   = id;                  // 0=q, 1=k, 2=v

    const void* W = (w == 0) ? Wq : (w == 1) ? Wk : Wv;
    const size_t bh = (size_t)b * HH + h;

    // W frags once (A-operand for Q/K swapped form; B-operand for V)
    bf16x8 wb0[4], wb1[4];
#pragma unroll
    for (int t = 0; t < 4; ++t) {
        const size_t wrow = (size_t)(h * 64 + t * 16 + l16) * DD;
        wb0[t] = load8(W, wrow + quad * 8, f32);
        wb1[t] = load8(W, wrow + quad * 8 + 32, f32);
    }

    // RoPE frequency constants once per t (depend only on d)
    float frevA[4], frevB[4];
    if (w < 2) {
#pragma unroll
        for (int t = 0; t < 4; ++t) {
            const int dbase = t * 16 + quad * 4;      // even
            frevA[t] = __builtin_amdgcn_exp2f(
                -(float)dbase * (13.2877123795f / 64.0f)) * 0.15915494309f;
            frevB[t] = __builtin_amdgcn_exp2f(
                -(float)(dbase + 2) * (13.2877123795f / 64.0f)) * 0.15915494309f;
        }
    }

    for (int s4 = 0; s4 < 4; ++s4) {
        const int s0 = (st4 * 4 + s4) * 16;
        const size_t qrow = ((size_t)b * SS + s0 + l16) * DD;
        bf16x8 a0 = load8(q, qrow + quad * 8, f32);
        bf16x8 a1 = load8(q, qrow + quad * 8 + 32, f32);

        floatx4 cv[4];
#pragma unroll
        for (int t = 0; t < 4; ++t) {
            floatx4 acc = {0.f, 0.f, 0.f, 0.f};
            if (w < 2) {        // swapped: C[m=d_local][n=s_local]
                acc = mfma16(wb0[t], a0, acc);
                acc = mfma16(wb1[t], a1, acc);
            } else {            // unswapped: C[m=s_local][n=d_local]
                acc = mfma16(a0, wb0[t], acc);
                acc = mfma16(a1, wb1[t], acc);
            }
            cv[t] = acc;
        }

        if (w < 2) {
            bf16*  dst  = (w == 0) ? qh : kh;
            float* ndst = (w == 0) ? qn : kn;
            const float srowf = (float)(s0 + l16);
            float nacc = 0.f;
            bf16* drow = dst + (bh * SS + s0 + l16) * DD + quad * 4;
#pragma unroll
            for (int t = 0; t < 4; ++t) {
                float revA = srowf * frevA[t]; revA -= floorf(revA);
                float revB = srowf * frevB[t]; revB -= floorf(revB);
                const float snA = __builtin_amdgcn_sinf(revA);
                const float csA = __builtin_amdgcn_cosf(revA);
                const float snB = __builtin_amdgcn_sinf(revB);
                const float csB = __builtin_amdgcn_cosf(revB);
                const float x0 = cv[t][0], x1 = cv[t][1];
                const float x2 = cv[t][2], x3 = cv[t][3];
                const float r0 = x0 * csA - x1 * snA;
                const float r1 = x0 * snA + x1 * csA;
                const float r2 = x2 * csB - x3 * snB;
                const float r3 = x2 * snB + x3 * csB;
                nacc += r0 * r0 + r1 * r1 + r2 * r2 + r3 * r3;
                bf16x4 o; o[0]=(bf16)r0; o[1]=(bf16)r1; o[2]=(bf16)r2; o[3]=(bf16)r3;
                *reinterpret_cast<bf16x4*>(drow + t * 16) = o;
            }
            nacc += __shfl_xor(nacc, 16);
            nacc += __shfl_xor(nacc, 32);
            if (quad == 0) ndst[bh * SS + s0 + l16] = nacc;
        } else {
            // tile-major V: [bh][st][dhi=t][dlo=l16][klocal=quad*4+r]
            bf16* vrow = vt + ((size_t)bh * 128 + st4 * 4 + s4) * 1024
                       + l16 * 16 + quad * 4;
#pragma unroll
            for (int t = 0; t < 4; ++t) {
                bf16x4 pv;
#pragma unroll
                for (int r = 0; r < 4; ++r) pv[r] = (bf16)cv[t][r];
                *reinterpret_cast<bf16x4*>(vrow + t * 256) = pv;
            }
        }
    }
}

// ---------------------------------------------------------------------------
// Kernel 2 (EXACT R18 revert — R19's 64-key chunks regressed): LDS-staged
// attn, 32-key chunks, double-buffered 16 KB, one barrier per chunk.
// Block = 4 waves on 4 consecutive qt of one (bh, slot). K bank-swizzled.
// ---------------------------------------------------------------------------
__global__ __launch_bounds__(256) void attn_kernel(
    const bf16* __restrict__ qh, const bf16* __restrict__ kh,
    const bf16* __restrict__ vt, const float* __restrict__ qn,
    const float* __restrict__ kn, const void* __restrict__ gamma,
    bf16* __restrict__ partial, const int* __restrict__ flagp,
    int ksh, int pb)
{
    __shared__ __align__(16) char smem[16384];  // K: 2x4KB @0; V: 2x4KB @8192
    const int f32  = *flagp;
    const int tid  = threadIdx.x;
    const int wv   = tid >> 6;
    const int lane = tid & 63;
    const int l16  = lane & 15;
    const int quad = lane >> 4;

    // XCD-pinned: bh%8 == blockIdx%8; grid = 16 * pb blocks
    const int xcd  = blockIdx.x & 7;
    int sblk = blockIdx.x >> 3;
    const int half = (sblk >= pb) ? 1 : 0;
    const int bh   = xcd + (half << 3);
    sblk -= half * pb;
    // decode (q4, slot): quad-group q4 has ((q4*64+63)>>ksh)+1 active slots
    int q4 = 0;
    for (;;) {
        const int ns = ((q4 * 64 + 63) >> ksh) + 1;
        if (sblk < ns) break;
        sblk -= ns; ++q4;
    }
    const int slot = sblk;
    const int qt   = q4 * 4 + wv;
    const int s0   = qt * 16;
    const int tb   = slot << ksh;
    const int te   = min(tb + (1 << ksh), (q4 + 1) * 64);
    const int nch  = (te - tb) >> 5;    // block-uniform chunk count
    const int h    = bh & 7;

    const float cc = load1(gamma, h, f32) * SCALE * 1.4426950408889634f;

    const bf16* qbase = qh + ((size_t)bh * SS + s0 + l16) * DD;
    bf16x8 aq0 = *reinterpret_cast<const bf16x8*>(qbase + quad * 8);
    bf16x8 aq1 = *reinterpret_cast<const bf16x8*>(qbase + quad * 8 + 32);
    const float qn_l = qn[(size_t)bh * SS + s0 + l16];

    floatx4 acc0 = {0.f,0.f,0.f,0.f}, acc1 = {0.f,0.f,0.f,0.f};
    floatx4 acc2 = {0.f,0.f,0.f,0.f}, acc3 = {0.f,0.f,0.f,0.f};

    const float* knp   = kn + (size_t)bh * SS + quad * 4;       // + key
    const char* kgbase = (const char*)(kh + (size_t)bh * SS * DD);  // + t0*128
    const char* vgbase = (const char*)(vt + (size_t)bh * 131072);   // + kt*2048

    // staging maps (loop-invariant): lane stages LDS cell jK = wv*64+lane
    const int jK   = wv * 64 + lane;
    const int keyK = jK >> 3;
    const int cK   = ((jK & 7) - keyK) & 7;
    const int goffK = keyK * 128 + cK * 16;    // swizzled K source (bytes)
    const int goffV = jK * 16;                 // V identity copy
    char* ldsK = smem + wv * 1024;             // + buf*4096
    char* ldsV = smem + 8192 + wv * 1024;      // + buf*4096

    // swizzled K frag offsets (bytes within a 4KB K buffer)
    const int kro0 = (l16 * 8 + ((quad + l16) & 7)) * 16;
    const int kro1 = (l16 * 8 + ((quad + 4 + l16) & 7)) * 16;
    const int vro  = l16 * 32 + quad * 8;      // + nb*512 (+2048 for sub1)

    // prologue: stage chunk 0 into buf 0
    GLL(kgbase + (size_t)tb * 128 + goffK, ldsK);
    GLL(vgbase + (size_t)(tb >> 4) * 2048 + goffV, ldsV);
    __syncthreads();

    int buf = 0, t0 = tb;
    for (int c = 0; c < nch; ++c, t0 += 32) {
        if (c + 1 < nch) {   // async prefetch next chunk into other buffer
            GLL(kgbase + (size_t)(t0 + 32) * 128 + goffK, ldsK + ((buf ^ 1) << 12));
            GLL(vgbase + (size_t)((t0 + 32) >> 4) * 2048 + goffV, ldsV + ((buf ^ 1) << 12));
        }
        const float4 knv0 = *reinterpret_cast<const float4*>(knp + t0);
        const float4 knv1 = *reinterpret_cast<const float4*>(knp + t0 + 16);
        const char* Kb = smem + (buf << 12);
        const char* Vb = smem + 8192 + (buf << 12);

        bf16x8 kc0 = *reinterpret_cast<const bf16x8*>(Kb + kro0);
        bf16x8 kc1 = *reinterpret_cast<const bf16x8*>(Kb + kro1);
        bf16x8 kc2 = *reinterpret_cast<const bf16x8*>(Kb + 2048 + kro0);
        bf16x8 kc3 = *reinterpret_cast<const bf16x8*>(Kb + 2048 + kro1);
        bf16x4 v00 = *reinterpret_cast<const bf16x4*>(Vb + vro);
        bf16x4 v01 = *reinterpret_cast<const bf16x4*>(Vb + 512 + vro);
        bf16x4 v02 = *reinterpret_cast<const bf16x4*>(Vb + 1024 + vro);
        bf16x4 v03 = *reinterpret_cast<const bf16x4*>(Vb + 1536 + vro);
        bf16x4 v10 = *reinterpret_cast<const bf16x4*>(Vb + 2048 + vro);
        bf16x4 v11 = *reinterpret_cast<const bf16x4*>(Vb + 2560 + vro);
        bf16x4 v12 = *reinterpret_cast<const bf16x4*>(Vb + 3072 + vro);
        bf16x4 v13 = *reinterpret_cast<const bf16x4*>(Vb + 3584 + vro);

        floatx4 z0 = {0.f,0.f,0.f,0.f};
        z0 = mfma16(kc0, aq0, z0);
        z0 = mfma16(kc1, aq1, z0);
        floatx4 z1 = {0.f,0.f,0.f,0.f};
        z1 = mfma16(kc2, aq0, z1);
        z1 = mfma16(kc3, aq1, z1);

        const float* k0_ = (const float*)&knv0;
        const float* k1_ = (const float*)&knv1;
        bf16x4 p0, p1;
        if (t0 + 31 <= s0) {                 // fully causal for this wave
#pragma unroll
            for (int i = 0; i < 4; ++i) {
                float rawA = fmaf(-2.f, z0[i], qn_l + k0_[i]);
                float rawB = fmaf(-2.f, z1[i], qn_l + k1_[i]);
                p0[i] = (bf16)__builtin_amdgcn_exp2f(fminf(-cc * rawA, 0.f));
                p1[i] = (bf16)__builtin_amdgcn_exp2f(fminf(-cc * rawB, 0.f));
            }
        } else {                             // diagonal/acausal: key<=query
            const int dq0 = s0 + l16 - t0 - quad * 4;
            const int dq1 = dq0 - 16;
#pragma unroll
            for (int i = 0; i < 4; ++i) {
                float rawA = fmaf(-2.f, z0[i], qn_l + k0_[i]);
                float rawB = fmaf(-2.f, z1[i], qn_l + k1_[i]);
                float eA = __builtin_amdgcn_exp2f(fminf(-cc * rawA, 0.f));
                float eB = __builtin_amdgcn_exp2f(fminf(-cc * rawB, 0.f));
                p0[i] = (bf16)((i <= dq0) ? eA : 0.f);
                p1[i] = (bf16)((i <= dq1) ? eB : 0.f);
            }
        }

        PV_MFMA(acc0, v00, p0);
        PV_MFMA(acc1, v01, p0);
        PV_MFMA(acc2, v02, p0);
        PV_MFMA(acc3, v03, p0);
        PV_MFMA(acc0, v10, p1);
        PV_MFMA(acc1, v11, p1);
        PV_MFMA(acc2, v12, p1);
        PV_MFMA(acc3, v13, p1);

        __syncthreads();    // staging done + all reads of buf done
        buf ^= 1;
    }

    MFMA_DRAIN4(acc0, acc1, acc2, acc3);

    // O^T C-frag: col=query=l16, row=d_local=quad*4+r -> bf16x4 per nb.
    bf16* pbp = partial + (size_t)slot * PSLOT
              + ((size_t)bh * SS + s0 + l16) * DD + quad * 4;
    bf16x4 o;
#define STORE4(PTR, ACC) \
    o[0]=(bf16)(ACC)[0]; o[1]=(bf16)(ACC)[1]; o[2]=(bf16)(ACC)[2]; o[3]=(bf16)(ACC)[3]; \
    *reinterpret_cast<bf16x4*>(PTR) = o;
    STORE4(pbp +  0, acc0)
    STORE4(pbp + 16, acc1)
    STORE4(pbp + 32, acc2)
    STORE4(pbp + 48, acc3)
#undef STORE4
}

// ---------------------------------------------------------------------------
// Kernel 3 (validated, unchanged): fused split-K reduce + output projection.
// ---------------------------------------------------------------------------
template <int NACT>
__device__ __forceinline__ floatx4 opj_core(const bf16* __restrict__ partial,
                                            const void* __restrict__ Wo,
                                            int b, int srow, size_t brow,
                                            int f32, int quad) {
    floatx4 acc = {0.f, 0.f, 0.f, 0.f};
#pragma unroll 4
    for (int kk = 0; kk < HD; kk += 32) {
        const int h  = kk >> 6;
        const int d0 = (kk & 63) + quad * 8;
        const bf16* ap = partial + (((size_t)(b * 8 + h)) * SS + srow) * 64 + d0;
        bf16x8 v0 = *reinterpret_cast<const bf16x8*>(ap);
        float u[8];
#pragma unroll
        for (int i = 0; i < 8; ++i) u[i] = (float)v0[i];
#pragma unroll
        for (int s = 1; s < NACT; ++s) {
            bf16x8 vs = *reinterpret_cast<const bf16x8*>(ap + (size_t)s * PSLOT);
#pragma unroll
            for (int i = 0; i < 8; ++i) u[i] += (float)vs[i];
        }
        bf16x8 a;
#pragma unroll
        for (int i = 0; i < 8; ++i) a[i] = (bf16)u[i];
        bf16x8 w = load8(Wo, brow + kk, f32);
        acc = mfma16(a, w, acc);
    }
    return acc;
}

__global__ __launch_bounds__(256) void outproj_kernel(
    const bf16* __restrict__ partial, const void* __restrict__ Wo,
    void* __restrict__ out, const int* __restrict__ flagp, int ksh)
{
    const int f32  = *flagp;
    const int ct   = threadIdx.x >> 6;
    const int lane = threadIdx.x & 63;
    const int l16  = lane & 15;
    const int quad = lane >> 4;

    const int g0   = blockIdx.x * 16;          // global row (b*SS + s)
    const int b    = g0 >> 11;
    const int s0   = g0 & (SS - 1);
    const int nact = (s0 >> ksh) + 1;
    const int srow = s0 + l16;
    const size_t brow = (size_t)(ct * 16 + l16) * HD + quad * 8;

    floatx4 acc;
    switch (nact) {
        case 1:  acc = opj_core<1>(partial, Wo, b, srow, brow, f32, quad); break;
        case 2:  acc = opj_core<2>(partial, Wo, b, srow, brow, f32, quad); break;
        case 3:  acc = opj_core<3>(partial, Wo, b, srow, brow, f32, quad); break;
        default: acc = opj_core<4>(partial, Wo, b, srow, brow, f32, quad); break;
    }

#pragma unroll
    for (int r = 0; r < 4; ++r) {
        const size_t o = (size_t)(g0 + quad * 4 + r) * DD + ct * 16 + l16;
        if (f32) ((float*)out)[o] = acc[r];
        else     ((bf16*)out)[o]  = (bf16)acc[r];
    }
}

// ---------------------------------------------------------------------------
extern "C" void kernel_launch(void* const* d_in, const int* in_sizes, int n_in,
                              void* d_out, int out_size, void* d_ws, size_t ws_size,
                              hipStream_t stream) {
    const void* q     = d_in[0];
    const void* Wq    = d_in[1];
    const void* Wk    = d_in[2];
    const void* Wv    = d_in[3];
    const void* Wo    = d_in[4];
    const void* gamma = d_in[5];

    char* ws = (char*)d_ws;
    bf16*  qh      = (bf16*)(ws);                    // 4 MiB
    bf16*  kh      = (bf16*)(ws + 4194304);          // 4 MiB
    bf16*  vt      = (bf16*)(ws + 8388608);          // 4 MiB (tile-major)
    float* qn      = (float*)(ws + 12582912);        // 128 KiB
    float* kn      = (float*)(ws + 12713984);        // 128 KiB
    int*   flag    = (int*)  (ws + 12845056);
    bf16*  partial = (bf16*)(ws + 13631488);         // nslot x 4 MiB (bf16)

    // split-K tier: 2 slots preferred (ksh=10) — R18 showed fewer slots win
    // (fewer partial writes, block prologues, reduce reads).
    int ksh = 11;
    const size_t base = 13631488ull;
    if (ws_size >= base + 2ull * 4194304) ksh = 10;

    // blocks per bh: one block per (qt-quad q4, active slot)
    int pb = 0;
    for (int q4 = 0; q4 < 32; ++q4) pb += ((q4 * 64 + 63) >> ksh) + 1;

    const int nproj = 3 * BB * HH * (SS / 64);       // 1536 proj work items
    proj_rope_kernel<<<dim3((nproj + 3) / 4), dim3(256), 0, stream>>>(
        q, Wq, Wk, Wv, qh, kh, vt, qn, kn, flag);
    // XCD-pinned grid: 8 xcds x 2 bh-halves x pb blocks
    attn_kernel<<<dim3(16 * pb), dim3(256), 0, stream>>>(
        qh, kh, vt, qn, kn, gamma, partial, flag, ksh, pb);
    outproj_kernel<<<dim3(BB * SS / 16), dim3(256), 0, stream>>>(
        partial, Wo, d_out, flag, ksh);
}